// Round 5
// baseline (542.994 us; speedup 1.0000x reference)
//
#include <hip/hip_runtime.h>

#define B_N  16
#define C_IN 1024
#define C_P  512
#define S_SP 1024
#define RED_BLOCKS 4480u

// c0 = exp(-2*gamma), gamma = 1e-4
#define C0_CONST 0.9998000199986667f

typedef float f32x4 __attribute__((ext_vector_type(4)));

// ---------------------------------------------------------------------------
// K1 redcoef_k: all reductions + (in the last-finishing block) the per-batch
// GroupNorm coefficient table. blockIdx.x ranges:
//   [0, 4096)      : xs[b][c] = sum_s x[b][c][s]        (one wave per row)
//   [4096, 4224)   : partial[oc][c] = sum_{o in 16-row chunk} Wg[o][c]
//   [4224, 4480)   : R[c] = sum_p Wz[c][p]              (one wave per row)
// Then: ticket = atomicAdd(counter); last block computes
//   wgc[c] = sum_oc partial[oc][c];  s0(b) = wgc . xs[b]
//   A_c = C0*s0*R_c; mu = mean_c A; var = mean_c A^2 - mu^2
//   coef[b][c] = (A_c - mu)*rsqrt(var+eps)*gn_w[c] + gn_b[c]
// ---------------------------------------------------------------------------
__global__ void redcoef_k(const float* __restrict__ x, const float* __restrict__ Wg,
                          const float* __restrict__ Wz, const float* __restrict__ gnw,
                          const float* __restrict__ gnb, float* __restrict__ xs,
                          float* __restrict__ partial, float* __restrict__ R,
                          float* __restrict__ coef, unsigned int* __restrict__ counter)
{
    const int bi   = blockIdx.x;
    const int tid  = threadIdx.x;
    const int lane = tid & 63, wv = tid >> 6;

    if (bi < 4096) {
        // ---- x row sums: row = b*1024 + c, 1024 floats per row ----
        const int row = bi * 4 + wv;
        const float* src = x + (size_t)row * S_SP;
        float s = 0.f;
#pragma unroll
        for (int j = 0; j < 4; ++j) {
            f32x4 v = *(const f32x4*)(src + j * 256 + lane * 4);
            s += (v[0] + v[1]) + (v[2] + v[3]);
        }
#pragma unroll
        for (int off = 32; off; off >>= 1) s += __shfl_down(s, off);
        if (lane == 0) xs[row] = s;
    } else if (bi < 4224) {
        // ---- Wg column partial sums (128 blocks: 4 c-groups x 32 o-chunks) ----
        const int i  = bi - 4096;
        const int cg = i & 3, oc = i >> 2;
        const int c  = cg * 256 + tid;
        float a = 0.f;
#pragma unroll
        for (int j = 0; j < 16; ++j)
            a += Wg[(size_t)(oc * 16 + j) * C_IN + c];
        partial[oc * C_IN + c] = a;
    } else {
        // ---- Wz row sums: one wave per row, 512 floats ----
        const int r = (bi - 4224) * 4 + wv;
        const float* row = Wz + (size_t)r * C_P;
        f32x4 v0 = *(const f32x4*)(row + lane * 8);
        f32x4 v1 = *(const f32x4*)(row + lane * 8 + 4);
        float s = ((v0[0] + v0[1]) + (v0[2] + v0[3])) +
                  ((v1[0] + v1[1]) + (v1[2] + v1[3]));
#pragma unroll
        for (int off = 32; off; off >>= 1) s += __shfl_down(s, off);
        if (lane == 0) R[r] = s;
    }

    // ---- last-block coef computation ----
    __threadfence();                      // publish this block's results
    __shared__ unsigned int ticket;
    if (tid == 0) ticket = atomicAdd(counter, 1u);
    __syncthreads();
    if (ticket != RED_BLOCKS - 1u) return;
    __threadfence();                      // acquire all published results

    // finish Wg colsum for this thread's 4 channels
    f32x4 wv4 = {0.f, 0.f, 0.f, 0.f};
#pragma unroll
    for (int oc = 0; oc < 32; ++oc) {
        f32x4 p = *(const f32x4*)(partial + oc * C_IN + tid * 4);
        wv4[0] += p[0]; wv4[1] += p[1]; wv4[2] += p[2]; wv4[3] += p[3];
    }
    f32x4 rv4 = *(const f32x4*)(R + tid * 4);
    f32x4 gw  = *(const f32x4*)(gnw + tid * 4);
    f32x4 gb  = *(const f32x4*)(gnb + tid * 4);

    // stats of R (batch-independent)
    float p1 = (rv4[0] + rv4[1]) + (rv4[2] + rv4[3]);
    float p2 = rv4[0] * rv4[0] + rv4[1] * rv4[1] + rv4[2] * rv4[2] + rv4[3] * rv4[3];
#pragma unroll
    for (int off = 32; off; off >>= 1) {
        p1 += __shfl_down(p1, off);
        p2 += __shfl_down(p2, off);
    }
    __shared__ float redm[2][4];
    __shared__ float redb[4];
    if (lane == 0) { redm[0][wv] = p1; redm[1][wv] = p2; }
    __syncthreads();
    const float Rsum = (redm[0][0] + redm[0][1]) + (redm[0][2] + redm[0][3]);
    const float Rsq  = (redm[1][0] + redm[1][1]) + (redm[1][2] + redm[1][3]);
    const float Rbar = Rsum * (1.0f / C_IN);
    const float Rvar = Rsq * (1.0f / C_IN) - Rbar * Rbar;

    for (int b = 0; b < B_N; ++b) {
        f32x4 xv4 = *(const f32x4*)(xs + b * C_IN + tid * 4);
        float p0 = wv4[0] * xv4[0] + wv4[1] * xv4[1] + wv4[2] * xv4[2] + wv4[3] * xv4[3];
#pragma unroll
        for (int off = 32; off; off >>= 1) p0 += __shfl_down(p0, off);
        if (lane == 0) redb[wv] = p0;
        __syncthreads();
        const float S0  = (redb[0] + redb[1]) + (redb[2] + redb[3]);
        const float K0  = C0_CONST * S0;
        const float mu  = K0 * Rbar;
        const float var = K0 * K0 * Rvar;
        const float rs  = rsqrtf(var + 1e-5f);
        f32x4 o;
#pragma unroll
        for (int e = 0; e < 4; ++e)
            o[e] = (K0 * rv4[e] - mu) * rs * gw[e] + gb[e];
        *(f32x4*)(coef + b * C_IN + tid * 4) = o;
        __syncthreads();
    }
}

// ---------------------------------------------------------------------------
// K2 add_k: out[b][c][s] = x[b][c][s] + coef[b][c].
// One block per (b,c) row; coef index block-uniform (scalar load).
// Nontemporal store for out (never re-read; keep x resident in L2/L3).
// grid 16384 x 256, f32x4/thread.
// ---------------------------------------------------------------------------
__global__ void add_k(const float* __restrict__ x, const float* __restrict__ coef,
                      float* __restrict__ out)
{
    const float a = coef[blockIdx.x];                 // uniform per block
    const int idx = blockIdx.x * 256 + threadIdx.x;   // vec4 index, [0, 4194304)
    f32x4 v = ((const f32x4*)x)[idx];
    f32x4 o;
    o[0] = v[0] + a; o[1] = v[1] + a; o[2] = v[2] + a; o[3] = v[3] + a;
    __builtin_nontemporal_store(o, (f32x4*)out + idx);
}

// ---------------------------------------------------------------------------
// Workspace: xs 64 KB @0, partial 128 KB @64K, R 4 KB @192K,
//            coef 64 KB @196K, counter 4 B @260K... (262144)
// ---------------------------------------------------------------------------
extern "C" void kernel_launch(void* const* d_in, const int* in_sizes, int n_in,
                              void* d_out, int out_size, void* d_ws, size_t ws_size,
                              hipStream_t stream)
{
    (void)in_sizes; (void)n_in; (void)out_size; (void)ws_size;
    const float* x  = (const float*)d_in[0];
    const float* Wg = (const float*)d_in[3];
    const float* Wz = (const float*)d_in[4];
    const float* gw = (const float*)d_in[5];
    const float* gb = (const float*)d_in[6];
    float* out = (float*)d_out;

    char* ws = (char*)d_ws;
    float*        xs      = (float*)(ws);
    float*        partial = (float*)(ws + 65536);
    float*        R       = (float*)(ws + 196608);
    float*        coef    = (float*)(ws + 200704);
    unsigned int* counter = (unsigned int*)(ws + 262144);

    hipMemsetAsync(counter, 0, sizeof(unsigned int), stream);
    redcoef_k<<<RED_BLOCKS, 256, 0, stream>>>(x, Wg, Wz, gw, gb, xs, partial, R, coef, counter);
    add_k    <<<16384,      256, 0, stream>>>(x, coef, out);
}